// Round 3
// baseline (243.542 us; speedup 1.0000x reference)
//
#include <hip/hip_runtime.h>

#define DIN 256
#define NTOK 4096

typedef __bf16 bf16;
typedef __bf16 bf16x4 __attribute__((ext_vector_type(4)));
typedef __bf16 bf16x8 __attribute__((ext_vector_type(8)));
typedef float floatx16 __attribute__((ext_vector_type(16)));

__device__ inline floatx16 mfma32(bf16x8 a, bf16x8 b, floatx16 c) {
    return __builtin_amdgcn_mfma_f32_32x32x16_bf16(a, b, c, 0, 0, 0);
}

// async global->LDS, 16B per lane. g: per-lane global addr; l: wave-uniform LDS base.
__device__ inline void async16(const void* g, void* l) {
    __builtin_amdgcn_global_load_lds(
        (const __attribute__((address_space(1))) unsigned int*)g,
        (__attribute__((address_space(3))) unsigned int*)l, 16, 0, 0);
}

// ---------------- kernel 1: cast weights to bf16 ----------------
__global__ void convert_w(const float* __restrict__ wq, const float* __restrict__ wk,
                          const float* __restrict__ wv, bf16* __restrict__ Wb) {
    int i = blockIdx.x * 256 + threadIdx.x;   // 0..196607
    const float* src = (i < 65536) ? wq : (i < 131072 ? wk : wv);
    Wb[i] = (bf16)src[i & 65535];
}

// ---------------- kernel 2: QKV projection, v2 (unchanged from R2; ~floor) ----------------
__global__ __launch_bounds__(256, 2) void proj_kernel(
    const float* __restrict__ x, const bf16* __restrict__ Wb,
    bf16* __restrict__ Qo, bf16* __restrict__ Ko, bf16* __restrict__ Vo)
{
    __shared__ __attribute__((aligned(16))) char smem[33792 + 32768];
    bf16 (*xs)[264] = (bf16(*)[264])smem;
    bf16* bufB = (bf16*)smem;
    bf16* bufA = (bf16*)(smem + 33792);

    int bid = blockIdx.x;
    int b = bid & 7, nt = bid >> 3;
    int n0 = nt * 64;
    int t = threadIdx.x;
    int lane = t & 63, w = t >> 6;
    int l32 = lane & 31, h = lane >> 5;
    int hl = lane >> 5;
    int tokg = w >> 1;
    int og   = w & 1;

    int wofs[8];
#pragma unroll
    for (int jj = 0; jj < 8; ++jj) {
        int q = w * 8 + jj;
        int r2 = 2 * q + hl;
        int cs = (l32) ^ (r2 & 31);
        wofs[jj] = r2 * 512 + cs * 16;
    }

    {
        const float* xb = x + (size_t)b * DIN * NTOK;
#pragma unroll
        for (int it = 0; it < 16; ++it) {
            int flat = it * 256 + t;
            int c = flat >> 4;
            int nf = flat & 15;
            float4 v = *(const float4*)(xb + (size_t)c * NTOK + n0 + nf * 4);
            int nn = nf * 4;
            xs[nn + 0][c] = (bf16)v.x;
            xs[nn + 1][c] = (bf16)v.y;
            xs[nn + 2][c] = (bf16)v.z;
            xs[nn + 3][c] = (bf16)v.w;
        }
    }
    __syncthreads();

    {
        const char* src = (const char*)Wb;
#pragma unroll
        for (int jj = 0; jj < 8; ++jj)
            async16(src + wofs[jj], (char*)bufA + (w * 8 + jj) * 1024);
    }

    bf16x8 xf[16];
#pragma unroll
    for (int ks = 0; ks < 16; ++ks)
        xf[ks] = *(const bf16x8*)&xs[tokg * 32 + l32][ks * 16 + h * 8];

    __syncthreads();

    for (int p = 0; p < 12; ++p) {
        if (p < 11) {
            bf16* nb = ((p + 1) & 1) ? bufB : bufA;
            const char* src = (const char*)Wb + (size_t)(p + 1) * 32768;
#pragma unroll
            for (int jj = 0; jj < 8; ++jj)
                async16(src + wofs[jj], (char*)nb + (w * 8 + jj) * 1024);
        }

        const bf16* wb = (p & 1) ? bufB : bufA;
        const bf16* Wrd = wb + (og * 32 + l32) * 256;
        int mat = p >> 2, dg = p & 3;

        floatx16 acc;
#pragma unroll
        for (int i = 0; i < 16; ++i) acc[i] = 0.0f;

        if (mat < 2) {
#pragma unroll
            for (int ks = 0; ks < 16; ++ks) {
                bf16x8 wf = *(const bf16x8*)(Wrd + (((2 * ks + h) ^ l32) * 8));
                acc = mfma32(xf[ks], wf, acc);
            }
            bf16* Out = (mat == 0 ? Qo : Ko) + (size_t)b * NTOK * DIN;
            int d = dg * 64 + og * 32 + l32;
#pragma unroll
            for (int r = 0; r < 16; ++r) {
                int tok = n0 + tokg * 32 + (r & 3) + 8 * (r >> 2) + 4 * h;
                Out[(size_t)tok * DIN + d] = (bf16)acc[r];
            }
        } else {
#pragma unroll
            for (int ks = 0; ks < 16; ++ks) {
                bf16x8 wf = *(const bf16x8*)(Wrd + (((2 * ks + h) ^ l32) * 8));
                acc = mfma32(wf, xf[ks], acc);
            }
            bf16* Out = Vo + (size_t)b * DIN * NTOK;
            int tok = n0 + tokg * 32 + l32;
#pragma unroll
            for (int r = 0; r < 16; ++r) {
                int d = dg * 64 + og * 32 + (r & 3) + 8 * (r >> 2) + 4 * h;
                Out[(size_t)d * NTOK + tok] = (bf16)acc[r];
            }
        }
        __syncthreads();
    }
}

// ---------------- kernel 3: attention v3 ----------------
// R2 diagnosis: per-iter 5600cyc = MFMA 2066 (37% = measured MfmaUtil) + LDS ~2700
// (232KB/iter @ ~85B/cyc + 6.3M conflict cyc) + VALU 24% -> pipes near-serial,
// LDS largest. v3: V moved out of LDS entirely (global->reg, L2-hot: 2MB/batch
// shared by 32 same-XCD blocks). Removes V DMA-writes (32KB) + va LDS reads
// (32KB) = -28% LDS traffic. Consumers prefetch iter mt+1's V fragments at top
// of iter mt; the per-iter barrier's vmcnt(0) drain is the pipeline wait (T14).
// Explicit 2x mt-unroll keeps vaA/vaB indexing static (rule #20, no scratch).
// T5 setprio around MFMA clusters (true role-split: each SIMD pairs 1 producer
// + 1 consumer). LDS now 96KB (Ks 64 + Ps 32); still 1 block/CU; VGPR budget
// 256 at 2 waves/SIMD -> consumer ~205 fits. Watch: WRITE_SIZE must stay 32MB
// (jump = spill, R1 lesson).
__global__ __launch_bounds__(512, 2) void attn_kernel(
    const bf16* __restrict__ Q, const bf16* __restrict__ K,
    const bf16* __restrict__ V, float* __restrict__ out)
{
    __shared__ bf16 Ks[2][64][256];   // 64 KB
    __shared__ bf16 Ps[2][128][64];   // 32 KB  (total 96 KB)

    int bid = blockIdx.x;
    int b = bid & 7, qt = bid >> 3;   // batch -> XCD L2 locality
    int n0 = qt * 128;
    int t = threadIdx.x, lane = t & 63, w = t >> 6;
    int l32 = lane & 31, h = lane >> 5;
    int lkey = (l32 & 7) ^ ((l32 >> 3) & 3);   // swizzle key at every use site

    const bf16* Qb = Q + (size_t)b * NTOK * DIN;
    const bf16* Kb = K + (size_t)b * NTOK * DIN;
    const bf16* Vb = V + (size_t)b * DIN * NTOK;
    float* Lp = (float*)&Ps[0][0][0];   // reused AFTER last tile barrier (Ps dead)

    if (w < 4) {
        // ================= S-producer: S^T = K.Q^T (unchanged) =================
        int tokg = w >> 1, mg = w & 1;
        int krow = mg * 32 + l32;

        int koff[8];
#pragma unroll
        for (int jj = 0; jj < 8; ++jj) {
            int q = w * 8 + jj;
            int r = q * 2 + (lane >> 5);
            int ck = (lane & 31) ^ ((r & 7) ^ ((r >> 3) & 3));
            koff[jj] = (r * 256 + ck * 8) * 2;
        }

        bf16x8 qf[2][16];
#pragma unroll
        for (int ca = 0; ca < 2; ++ca) {
            const bf16* qrow = Qb + (size_t)(n0 + tokg * 64 + ca * 32 + l32) * DIN + h * 8;
#pragma unroll
            for (int ks = 0; ks < 16; ++ks) qf[ca][ks] = *(const bf16x8*)(qrow + ks * 16);
        }

        float lsum[2] = {0.0f, 0.0f};

        // prologue: K(0)->buf0, K(1)->buf1
#pragma unroll
        for (int jj = 0; jj < 8; ++jj) {
            async16((const char*)Kb + koff[jj], (bf16*)Ks[0] + (w * 8 + jj) * 512);
            async16((const char*)Kb + 32768 + koff[jj], (bf16*)Ks[1] + (w * 8 + jj) * 512);
        }
        __syncthreads();   // (1)

        // S^T(0) -> Ps[0]
        {
            const bf16* Krd = (const bf16*)Ks[0] + krow * 256;
            floatx16 st[2];
#pragma unroll
            for (int i = 0; i < 16; ++i) { st[0][i] = 0.0f; st[1][i] = 0.0f; }
            __builtin_amdgcn_s_setprio(1);
#pragma unroll
            for (int ks = 0; ks < 16; ++ks) {
                bf16x8 kf = *(const bf16x8*)(Krd + (((2 * ks + h) ^ lkey) * 8));
                st[0] = mfma32(kf, qf[0][ks], st[0]);
                st[1] = mfma32(kf, qf[1][ks], st[1]);
            }
            __builtin_amdgcn_s_setprio(0);
#pragma unroll
            for (int ca = 0; ca < 2; ++ca) {
                bf16* Prow = (bf16*)Ps[0] + (tokg * 64 + ca * 32 + l32) * 64;
                float tsum = 0.0f;
#pragma unroll
                for (int g = 0; g < 4; ++g) {
                    bf16x4 pk;
#pragma unroll
                    for (int i = 0; i < 4; ++i) {
                        float e = __expf(st[ca][g * 4 + i] * 0.0625f);
                        tsum += e;
                        pk[i] = (bf16)e;
                    }
                    *(bf16x4*)((char*)Prow + (((mg * 4 + g) ^ lkey) * 16) + h * 8) = pk;
                }
                lsum[ca] += tsum;
            }
        }
        __syncthreads();   // (2)

        for (int mt = 0; mt < 64; ++mt) {
            if (mt < 62) {   // DMA K(mt+2) -> Ks[mt&1]
                int kadd = (mt + 2) * 32768;
#pragma unroll
                for (int jj = 0; jj < 8; ++jj)
                    async16((const char*)Kb + kadd + koff[jj],
                            (bf16*)Ks[mt & 1] + (w * 8 + jj) * 512);
            }
            if (mt < 63) {
                const bf16* Krd = (const bf16*)Ks[(mt + 1) & 1] + krow * 256;
                floatx16 st[2];
#pragma unroll
                for (int i = 0; i < 16; ++i) { st[0][i] = 0.0f; st[1][i] = 0.0f; }
                __builtin_amdgcn_s_setprio(1);
#pragma unroll
                for (int ks = 0; ks < 16; ++ks) {
                    bf16x8 kf = *(const bf16x8*)(Krd + (((2 * ks + h) ^ lkey) * 8));
                    st[0] = mfma32(kf, qf[0][ks], st[0]);
                    st[1] = mfma32(kf, qf[1][ks], st[1]);
                }
                __builtin_amdgcn_s_setprio(0);
                bf16* Pw = (bf16*)Ps[(mt + 1) & 1];
#pragma unroll
                for (int ca = 0; ca < 2; ++ca) {
                    bf16* Prow = Pw + (tokg * 64 + ca * 32 + l32) * 64;
                    float tsum = 0.0f;
#pragma unroll
                    for (int g = 0; g < 4; ++g) {
                        bf16x4 pk;
#pragma unroll
                        for (int i = 0; i < 4; ++i) {
                            float e = __expf(st[ca][g * 4 + i] * 0.0625f);
                            tsum += e;
                            pk[i] = (bf16)e;
                        }
                        *(bf16x4*)((char*)Prow + (((mg * 4 + g) ^ lkey) * 16) + h * 8) = pk;
                    }
                    lsum[ca] += tsum;
                }
            }
            __syncthreads();   // single barrier per iter
        }

        // epilogue: h-pair reduce, publish row sums (Ps now dead -> Lp alias ok)
#pragma unroll
        for (int ca = 0; ca < 2; ++ca) {
            float sv = lsum[ca];
            sv += __shfl_xor(sv, 32);
            if (h == 0) Lp[mg * 128 + tokg * 64 + ca * 32 + l32] = sv;
        }
        __syncthreads();   // (3)
    } else {
        // ========== PV-consumer: O^T = V^T.P^T, V from global (L2) to regs ==========
        int slab = w - 4;

        // global V^T row pointers for this wave's two d-rows (dc=0,1), col chunk by (kst,h)
        const bf16* Vr0 = Vb + (size_t)(slab * 64 + l32) * NTOK + h * 8;
        const bf16* Vr1 = Vb + (size_t)(slab * 64 + 32 + l32) * NTOK + h * 8;

        floatx16 oacc[8];   // [dc*4+tc]
#pragma unroll
        for (int i = 0; i < 8; ++i)
            for (int j = 0; j < 16; ++j) oacc[i][j] = 0.0f;

        bf16x8 vaA[8], vaB[8];   // [dc*4+kst]; double-buffered V fragments
        // preload iter 0 -> vaA
#pragma unroll
        for (int kst = 0; kst < 4; ++kst) {
            vaA[kst]     = *(const bf16x8*)(Vr0 + kst * 16);
            vaA[4 + kst] = *(const bf16x8*)(Vr1 + kst * 16);
        }
        __syncthreads();   // (1)
        __syncthreads();   // (2)

#pragma unroll 1
        for (int mt2 = 0; mt2 < 32; ++mt2) {
            int mt = mt2 * 2;
            // ---- body A: use vaA (tile mt, Ps[0]); prefetch tile mt+1 -> vaB ----
            {
                int nn = (mt + 1) * 64;
#pragma unroll
                for (int kst = 0; kst < 4; ++kst) {
                    vaB[kst]     = *(const bf16x8*)(Vr0 + nn + kst * 16);
                    vaB[4 + kst] = *(const bf16x8*)(Vr1 + nn + kst * 16);
                }
                const char* Prd = (const char*)Ps[0];
#pragma unroll
                for (int kst = 0; kst < 4; ++kst) {
                    bf16x8 pb[4];
#pragma unroll
                    for (int tc = 0; tc < 4; ++tc)
                        pb[tc] = *(const bf16x8*)(Prd + (tc * 32 + l32) * 128 +
                                                  (((kst * 2 + h) ^ lkey) * 16));
                    __builtin_amdgcn_s_setprio(1);
#pragma unroll
                    for (int tc = 0; tc < 4; ++tc) {
                        oacc[tc]     = mfma32(vaA[kst],     pb[tc], oacc[tc]);
                        oacc[4 + tc] = mfma32(vaA[4 + kst], pb[tc], oacc[4 + tc]);
                    }
                    __builtin_amdgcn_s_setprio(0);
                }
                __syncthreads();
            }
            // ---- body B: use vaB (tile mt+1, Ps[1]); prefetch tile mt+2 -> vaA ----
            {
                if (mt2 < 31) {
                    int nn = (mt + 2) * 64;
#pragma unroll
                    for (int kst = 0; kst < 4; ++kst) {
                        vaA[kst]     = *(const bf16x8*)(Vr0 + nn + kst * 16);
                        vaA[4 + kst] = *(const bf16x8*)(Vr1 + nn + kst * 16);
                    }
                }
                const char* Prd = (const char*)Ps[1];
#pragma unroll
                for (int kst = 0; kst < 4; ++kst) {
                    bf16x8 pb[4];
#pragma unroll
                    for (int tc = 0; tc < 4; ++tc)
                        pb[tc] = *(const bf16x8*)(Prd + (tc * 32 + l32) * 128 +
                                                  (((kst * 2 + h) ^ lkey) * 16));
                    __builtin_amdgcn_s_setprio(1);
#pragma unroll
                    for (int tc = 0; tc < 4; ++tc) {
                        oacc[tc]     = mfma32(vaB[kst],     pb[tc], oacc[tc]);
                        oacc[4 + tc] = mfma32(vaB[4 + kst], pb[tc], oacc[4 + tc]);
                    }
                    __builtin_amdgcn_s_setprio(0);
                }
                __syncthreads();
            }
        }

        __syncthreads();   // (3): Lp ready
        float* ob = out + (size_t)b * DIN * NTOK;
#pragma unroll
        for (int tc = 0; tc < 4; ++tc) {
            int tok = tc * 32 + l32;
            float rinv = 1.0f / (Lp[tok] + Lp[128 + tok]);
#pragma unroll
            for (int dc = 0; dc < 2; ++dc)
#pragma unroll
                for (int r = 0; r < 16; ++r) {
                    int d = slab * 64 + dc * 32 + (r & 3) + 8 * (r >> 2) + 4 * h;
                    ob[(size_t)d * NTOK + n0 + tok] = oacc[dc * 4 + tc][r] * rinv;
                }
        }
    }
}

// ---------------- launcher ----------------
extern "C" void kernel_launch(void* const* d_in, const int* in_sizes, int n_in,
                              void* d_out, int out_size, void* d_ws, size_t ws_size,
                              hipStream_t stream) {
    const float* x  = (const float*)d_in[0];
    const float* wq = (const float*)d_in[1];
    const float* wk = (const float*)d_in[2];
    const float* wv = (const float*)d_in[3];
    float* outf = (float*)d_out;

    char* ws = (char*)d_ws;
    bf16* Wb = (bf16*)(ws);                                  // 384 KB
    bf16* Qp = (bf16*)(ws + (1u << 20));                     // 16 MB
    bf16* Kp = (bf16*)(ws + (1u << 20) + (16u << 20));       // 16 MB
    bf16* Vp = (bf16*)(ws + (1u << 20) + (32u << 20));       // 16 MB

    convert_w<<<768, 256, 0, stream>>>(wq, wk, wv, Wb);
    proj_kernel<<<512, 256, 0, stream>>>(x, Wb, Qp, Kp, Vp);
    attn_kernel<<<256, 512, 0, stream>>>(Qp, Kp, Vp, outf);
}

// Round 4
// 237.381 us; speedup vs baseline: 1.0260x; 1.0260x over previous
//
#include <hip/hip_runtime.h>

#define DIN 256
#define NTOK 4096

typedef __bf16 bf16;
typedef __bf16 bf16x4 __attribute__((ext_vector_type(4)));
typedef __bf16 bf16x8 __attribute__((ext_vector_type(8)));
typedef float floatx16 __attribute__((ext_vector_type(16)));

__device__ inline floatx16 mfma32(bf16x8 a, bf16x8 b, floatx16 c) {
    return __builtin_amdgcn_mfma_f32_32x32x16_bf16(a, b, c, 0, 0, 0);
}

// async global->LDS, 16B per lane. g: per-lane global addr; l: wave-uniform LDS base.
__device__ inline void async16(const void* g, void* l) {
    __builtin_amdgcn_global_load_lds(
        (const __attribute__((address_space(1))) unsigned int*)g,
        (__attribute__((address_space(3))) unsigned int*)l, 16, 0, 0);
}

// ---------------- kernel 1: cast weights to bf16 ----------------
__global__ void convert_w(const float* __restrict__ wq, const float* __restrict__ wk,
                          const float* __restrict__ wv, bf16* __restrict__ Wb) {
    int i = blockIdx.x * 256 + threadIdx.x;   // 0..196607
    const float* src = (i < 65536) ? wq : (i < 131072 ? wk : wv);
    Wb[i] = (bf16)src[i & 65535];
}

// ---------------- kernel 2: QKV projection v3b ----------------
// R3 analysis: proj ran ~45us (vs 5us matrix floor) due to 12 barrier-phases with
// only 16 MFMA/wave between full vmcnt(0)+barrier drains, and 4:1 W:output traffic.
// v3b: 128 tokens/block (grid 256 = 1/CU, 8 waves), 128-row W tiles -> 6 phases,
// 32 MFMA/wave between barriers (2x drain amortization), W re-read traffic halved.
// W staged via global_load_lds 16B: linear LDS dest + pre-swizzled global source,
// reads apply the same XOR (involution, key = row&31 on 16B chunks). x tile LDS
// (67.6KB) is aliased under the two 64KB W buffers (dead once xf is in regs).
__global__ __launch_bounds__(512, 2) void proj_kernel(
    const float* __restrict__ x, const bf16* __restrict__ Wb,
    bf16* __restrict__ Qo, bf16* __restrict__ Ko, bf16* __restrict__ Vo)
{
    // [0,65536): W bufA ; [65536,131072): W bufB ; xs[128][264] (67.6KB) spans both (dies first)
    __shared__ __attribute__((aligned(16))) char smem[131072];
    bf16 (*xs)[264] = (bf16(*)[264])smem;
    bf16* bufA = (bf16*)smem;
    bf16* bufB = (bf16*)(smem + 65536);

    int bid = blockIdx.x;
    int b = bid & 7, nt = bid >> 3;    // 8 batches x 32 token-tiles
    int n0 = nt * 128;
    int t = threadIdx.x;
    int lane = t & 63, w = t >> 6;     // 8 waves
    int l32 = lane & 31, h = lane >> 5;
    int tokg = w >> 1;                 // 0..3: 32-token group
    int og   = w & 1;                  // 0..1: 64-row half of the 128-row W tile

    // W staging: q = w*8+jj covers rows 2q,2q+1 (wave w stages rows 16w..16w+15).
    // lane l -> row r2 = 2q + (l>>5), LDS chunk l&31; source chunk = (l&31)^(r2&31).
    int wofs[8];
#pragma unroll
    for (int jj = 0; jj < 8; ++jj) {
        int q = w * 8 + jj;
        int r2 = 2 * q + h;
        int cs = l32 ^ (r2 & 31);
        wofs[jj] = r2 * 512 + cs * 16;   // bytes within a 64KB (128-row) tile
    }

    // ---- stage x tile (fp32 -> bf16, transposed to [tok][ch]), 128 tok x 256 ch ----
    {
        const float* xb = x + (size_t)b * DIN * NTOK;
#pragma unroll
        for (int it = 0; it < 16; ++it) {
            int flat = it * 512 + t;          // 0..8191
            int c = flat >> 5;                // 0..255
            int nf = flat & 31;               // 0..31 -> tok = nf*4..+3
            float4 v = *(const float4*)(xb + (size_t)c * NTOK + n0 + nf * 4);
            int nn = nf * 4;
            xs[nn + 0][c] = (bf16)v.x;
            xs[nn + 1][c] = (bf16)v.y;
            xs[nn + 2][c] = (bf16)v.z;
            xs[nn + 3][c] = (bf16)v.w;
        }
    }
    __syncthreads();

    bf16x8 xf[16];
#pragma unroll
    for (int ks = 0; ks < 16; ++ks)
        xf[ks] = *(const bf16x8*)&xs[tokg * 32 + l32][ks * 16 + h * 8];

    __syncthreads();   // all waves done reading xs -> region reusable as W bufs

    // ---- prologue: stage W tile 0 -> bufA ----
    {
        const char* src = (const char*)Wb;
#pragma unroll
        for (int jj = 0; jj < 8; ++jj)
            async16(src + wofs[jj], (char*)bufA + (w * 8 + jj) * 1024);
    }
    __syncthreads();   // drain tile 0

    // ---- 6 phases: p = mat*2 + dhalf ; W tile = rows dhalf*128..+127 of mat ----
    for (int p = 0; p < 6; ++p) {
        if (p < 5) {   // prefetch tile p+1 into the other buffer
            bf16* nb = ((p + 1) & 1) ? bufB : bufA;
            const char* src = (const char*)Wb + (size_t)(p + 1) * 65536;
#pragma unroll
            for (int jj = 0; jj < 8; ++jj)
                async16(src + wofs[jj], (char*)nb + (w * 8 + jj) * 1024);
        }

        const bf16* wb = (p & 1) ? bufB : bufA;
        int mat = p >> 1, dhalf = p & 1;

        floatx16 acc[2];
#pragma unroll
        for (int dc = 0; dc < 2; ++dc)
#pragma unroll
            for (int i = 0; i < 16; ++i) acc[dc][i] = 0.0f;

        if (mat < 2) {
#pragma unroll
            for (int ks = 0; ks < 16; ++ks) {
#pragma unroll
                for (int dc = 0; dc < 2; ++dc) {
                    int row = og * 64 + dc * 32 + l32;
                    bf16x8 wf = *(const bf16x8*)((const char*)wb + row * 512 +
                                                 (((2 * ks + h) ^ (row & 31)) * 16));
                    acc[dc] = mfma32(xf[ks], wf, acc[dc]);
                }
            }
            bf16* Out = (mat == 0 ? Qo : Ko) + (size_t)b * NTOK * DIN;
#pragma unroll
            for (int dc = 0; dc < 2; ++dc) {
                int d = dhalf * 128 + og * 64 + dc * 32 + l32;
#pragma unroll
                for (int r = 0; r < 16; ++r) {
                    int tok = n0 + tokg * 32 + (r & 3) + 8 * (r >> 2) + 4 * h;
                    Out[(size_t)tok * DIN + d] = (bf16)acc[dc][r];
                }
            }
        } else {
#pragma unroll
            for (int ks = 0; ks < 16; ++ks) {
#pragma unroll
                for (int dc = 0; dc < 2; ++dc) {
                    int row = og * 64 + dc * 32 + l32;
                    bf16x8 wf = *(const bf16x8*)((const char*)wb + row * 512 +
                                                 (((2 * ks + h) ^ (row & 31)) * 16));
                    acc[dc] = mfma32(wf, xf[ks], acc[dc]);
                }
            }
            bf16* Out = Vo + (size_t)b * DIN * NTOK;
            int tok = n0 + tokg * 32 + l32;
#pragma unroll
            for (int dc = 0; dc < 2; ++dc)
#pragma unroll
                for (int r = 0; r < 16; ++r) {
                    int d = dhalf * 128 + og * 64 + dc * 32 + (r & 3) + 8 * (r >> 2) + 4 * h;
                    Out[(size_t)d * NTOK + tok] = (bf16)acc[dc][r];
                }
        }
        __syncthreads();   // drains tile p+1 DMA; protects buffer reuse
    }
}

// ---------------- kernel 3: attention (byte-exact R2 version, 154us) ----------------
// Q,K: [B][N][256] bf16 ; V: [B][256][N] bf16 (=V^T) ; out: [B][256][N] fp32
// 512 thr = 8 waves. w<4: S-producers (tokg=w>>1, mg=w&1) compute S^T = K.Q^T
// (32m x 64tok), exp, b64-pack into Ps[(mt+1)&1]. w>=4: PV-consumers (slab=w-4)
// O^T[64d][128tok] from Ps[mt&1] + Vs[mt&1]. ONE barrier per iteration.
// All tiles use conflict-free swizzle: 16B chunk c of row r at pos c^(r&7)^((r>>3)&3).
__global__ __launch_bounds__(512, 2) void attn_kernel(
    const bf16* __restrict__ Q, const bf16* __restrict__ K,
    const bf16* __restrict__ V, float* __restrict__ out)
{
    __shared__ bf16 Ks[2][64][256];   // 64 KB
    __shared__ bf16 Vs[2][256][64];   // 64 KB
    __shared__ bf16 Ps[2][128][64];   // 32 KB  (total 160 KB exactly)

    int bid = blockIdx.x;
    int b = bid & 7, qt = bid >> 3;   // batch -> XCD L2 locality
    int n0 = qt * 128;
    int t = threadIdx.x, lane = t & 63, w = t >> 6;
    int l32 = lane & 31, h = lane >> 5;
    int lkey = (l32 & 7) ^ ((l32 >> 3) & 3);   // swizzle key at every use site

    const bf16* Qb = Q + (size_t)b * NTOK * DIN;
    const bf16* Kb = K + (size_t)b * NTOK * DIN;
    const bf16* Vb = V + (size_t)b * DIN * NTOK;
    float* Lp = (float*)&Ps[0][0][0];   // reused AFTER last tile barrier (Ps dead)

    if (w < 4) {
        // ================= S-producer: S^T = K.Q^T =================
        int tokg = w >> 1, mg = w & 1;
        int krow = mg * 32 + l32;

        int koff[8];
#pragma unroll
        for (int jj = 0; jj < 8; ++jj) {
            int q = w * 8 + jj;
            int r = q * 2 + (lane >> 5);
            int ck = (lane & 31) ^ ((r & 7) ^ ((r >> 3) & 3));
            koff[jj] = (r * 256 + ck * 8) * 2;
        }

        bf16x8 qf[2][16];
#pragma unroll
        for (int ca = 0; ca < 2; ++ca) {
            const bf16* qrow = Qb + (size_t)(n0 + tokg * 64 + ca * 32 + l32) * DIN + h * 8;
#pragma unroll
            for (int ks = 0; ks < 16; ++ks) qf[ca][ks] = *(const bf16x8*)(qrow + ks * 16);
        }

        float lsum[2] = {0.0f, 0.0f};

        // prologue: K(0)->buf0, K(1)->buf1
#pragma unroll
        for (int jj = 0; jj < 8; ++jj) {
            async16((const char*)Kb + koff[jj], (bf16*)Ks[0] + (w * 8 + jj) * 512);
            async16((const char*)Kb + 32768 + koff[jj], (bf16*)Ks[1] + (w * 8 + jj) * 512);
        }
        __syncthreads();   // (1)

        // S^T(0) -> Ps[0]
        {
            const bf16* Krd = (const bf16*)Ks[0] + krow * 256;
            floatx16 st[2];
#pragma unroll
            for (int i = 0; i < 16; ++i) { st[0][i] = 0.0f; st[1][i] = 0.0f; }
#pragma unroll
            for (int ks = 0; ks < 16; ++ks) {
                bf16x8 kf = *(const bf16x8*)(Krd + (((2 * ks + h) ^ lkey) * 8));
                st[0] = mfma32(kf, qf[0][ks], st[0]);
                st[1] = mfma32(kf, qf[1][ks], st[1]);
            }
#pragma unroll
            for (int ca = 0; ca < 2; ++ca) {
                bf16* Prow = (bf16*)Ps[0] + (tokg * 64 + ca * 32 + l32) * 64;
                float tsum = 0.0f;
#pragma unroll
                for (int g = 0; g < 4; ++g) {
                    bf16x4 pk;
#pragma unroll
                    for (int i = 0; i < 4; ++i) {
                        float e = __expf(st[ca][g * 4 + i] * 0.0625f);
                        tsum += e;
                        pk[i] = (bf16)e;
                    }
                    *(bf16x4*)((char*)Prow + (((mg * 4 + g) ^ lkey) * 16) + h * 8) = pk;
                }
                lsum[ca] += tsum;
            }
        }
        __syncthreads();   // (2)

        for (int mt = 0; mt < 64; ++mt) {
            if (mt < 62) {   // DMA K(mt+2) -> Ks[mt&1]
                int kadd = (mt + 2) * 32768;
#pragma unroll
                for (int jj = 0; jj < 8; ++jj)
                    async16((const char*)Kb + kadd + koff[jj],
                            (bf16*)Ks[mt & 1] + (w * 8 + jj) * 512);
            }
            if (mt < 63) {
                const bf16* Krd = (const bf16*)Ks[(mt + 1) & 1] + krow * 256;
                floatx16 st[2];
#pragma unroll
                for (int i = 0; i < 16; ++i) { st[0][i] = 0.0f; st[1][i] = 0.0f; }
#pragma unroll
                for (int ks = 0; ks < 16; ++ks) {
                    bf16x8 kf = *(const bf16x8*)(Krd + (((2 * ks + h) ^ lkey) * 8));
                    st[0] = mfma32(kf, qf[0][ks], st[0]);
                    st[1] = mfma32(kf, qf[1][ks], st[1]);
                }
                bf16* Pw = (bf16*)Ps[(mt + 1) & 1];
#pragma unroll
                for (int ca = 0; ca < 2; ++ca) {
                    bf16* Prow = Pw + (tokg * 64 + ca * 32 + l32) * 64;
                    float tsum = 0.0f;
#pragma unroll
                    for (int g = 0; g < 4; ++g) {
                        bf16x4 pk;
#pragma unroll
                        for (int i = 0; i < 4; ++i) {
                            float e = __expf(st[ca][g * 4 + i] * 0.0625f);
                            tsum += e;
                            pk[i] = (bf16)e;
                        }
                        *(bf16x4*)((char*)Prow + (((mg * 4 + g) ^ lkey) * 16) + h * 8) = pk;
                    }
                    lsum[ca] += tsum;
                }
            }
            __syncthreads();   // single barrier per iter
        }

        // epilogue: h-pair reduce, publish row sums (Ps now dead -> Lp alias ok)
#pragma unroll
        for (int ca = 0; ca < 2; ++ca) {
            float sv = lsum[ca];
            sv += __shfl_xor(sv, 32);
            if (h == 0) Lp[mg * 128 + tokg * 64 + ca * 32 + l32] = sv;
        }
        __syncthreads();   // (3)
    } else {
        // ================= PV-consumer: O^T = V^T.P^T =================
        int slab = w - 4;

        int vofs[8];
#pragma unroll
        for (int jj = 0; jj < 8; ++jj) {
            int q = slab * 8 + jj;
            int d = q * 8 + (lane >> 3);
            int cv = (lane & 7) ^ ((d & 7) ^ ((d >> 3) & 3));
            vofs[jj] = (d * 4096 + cv * 8) * 2;
        }

        floatx16 oacc[8];   // [dc][tc]
#pragma unroll
        for (int i = 0; i < 8; ++i)
            for (int j = 0; j < 16; ++j) oacc[i][j] = 0.0f;

        // prologue: V(0)->buf0
#pragma unroll
        for (int jj = 0; jj < 8; ++jj)
            async16((const char*)Vb + vofs[jj], (bf16*)Vs[0] + (slab * 8 + jj) * 512);
        __syncthreads();   // (1)
        __syncthreads();   // (2)

        for (int mt = 0; mt < 64; ++mt) {
            if (mt < 63) {   // DMA V(mt+1) -> Vs[(mt+1)&1]
                int vadd = (mt + 1) * 128;
#pragma unroll
                for (int jj = 0; jj < 8; ++jj)
                    async16((const char*)Vb + vadd + vofs[jj],
                            (bf16*)Vs[(mt + 1) & 1] + (slab * 8 + jj) * 512);
            }
            const bf16* Vrd = (const bf16*)Vs[mt & 1];
            const char* Prd = (const char*)Ps[mt & 1];
#pragma unroll
            for (int kst = 0; kst < 4; ++kst) {
                bf16x8 va[2], pb[4];
#pragma unroll
                for (int dc = 0; dc < 2; ++dc) {
                    int d = slab * 64 + dc * 32 + l32;
                    va[dc] = *(const bf16x8*)(Vrd + d * 64 + (((kst * 2 + h) ^ lkey) * 8));
                }
#pragma unroll
                for (int tc = 0; tc < 4; ++tc)
                    pb[tc] = *(const bf16x8*)(Prd + (tc * 32 + l32) * 128 +
                                              (((kst * 2 + h) ^ lkey) * 16));
#pragma unroll
                for (int dc = 0; dc < 2; ++dc)
#pragma unroll
                    for (int tc = 0; tc < 4; ++tc)
                        oacc[dc * 4 + tc] = mfma32(va[dc], pb[tc], oacc[dc * 4 + tc]);
            }
            __syncthreads();   // single barrier per iter
        }

        __syncthreads();   // (3): Lp ready
        float* ob = out + (size_t)b * DIN * NTOK;
#pragma unroll
        for (int tc = 0; tc < 4; ++tc) {
            int tok = tc * 32 + l32;
            float rinv = 1.0f / (Lp[tok] + Lp[128 + tok]);
#pragma unroll
            for (int dc = 0; dc < 2; ++dc)
#pragma unroll
                for (int r = 0; r < 16; ++r) {
                    int d = slab * 64 + dc * 32 + (r & 3) + 8 * (r >> 2) + 4 * h;
                    ob[(size_t)d * NTOK + n0 + tok] = oacc[dc * 4 + tc][r] * rinv;
                }
        }
    }
}

// ---------------- launcher ----------------
extern "C" void kernel_launch(void* const* d_in, const int* in_sizes, int n_in,
                              void* d_out, int out_size, void* d_ws, size_t ws_size,
                              hipStream_t stream) {
    const float* x  = (const float*)d_in[0];
    const float* wq = (const float*)d_in[1];
    const float* wk = (const float*)d_in[2];
    const float* wv = (const float*)d_in[3];
    float* outf = (float*)d_out;

    char* ws = (char*)d_ws;
    bf16* Wb = (bf16*)(ws);                                  // 384 KB
    bf16* Qp = (bf16*)(ws + (1u << 20));                     // 16 MB
    bf16* Kp = (bf16*)(ws + (1u << 20) + (16u << 20));       // 16 MB
    bf16* Vp = (bf16*)(ws + (1u << 20) + (32u << 20));       // 16 MB

    convert_w<<<768, 256, 0, stream>>>(wq, wk, wv, Wb);
    proj_kernel<<<256, 512, 0, stream>>>(x, Wb, Qp, Kp, Vp);
    attn_kernel<<<256, 512, 0, stream>>>(Qp, Kp, Vp, outf);
}